// Round 7
// baseline (877.136 us; speedup 1.0000x reference)
//
#include <hip/hip_runtime.h>
#include <hip/hip_bf16.h>
#include <hip/hip_fp16.h>

// Problem constants (fixed by setup_inputs)
#define S_   2048
#define H_   2048
#define ROOM 256
#define NH   16
#define HD   128   // head_dim
#define TD   2048  // total_dim

typedef __hip_bfloat16 hbf16;

// Runtime dtype codes
#define DT_F32  0
#define DT_BF16 1
#define DT_F16  2
// Operand selectors (resolved against detected mode)
#define SEL_F32   0
#define SEL_IN    1   // f32-mode: f32 ; bf16-mode: bf16
#define SEL_SCORE 2   // f32-mode: f32 ; bf16-mode: f16
#define SEL_OUT   3   // f32-mode: f32 ; bf16-mode: bf16

typedef __bf16    bf16x8 __attribute__((ext_vector_type(8)));
typedef _Float16  f16x8  __attribute__((ext_vector_type(8)));
typedef float     f32x4  __attribute__((ext_vector_type(4)));

__device__ __forceinline__ int resolveDT(int sel, int bf16mode) {
    if (sel == SEL_F32) return DT_F32;
    if (sel == SEL_SCORE) return bf16mode ? DT_F16 : DT_F32;
    return bf16mode ? DT_BF16 : DT_F32;
}
__device__ __forceinline__ float loadF(const void* p, long i, int dt) {
    if (dt == DT_F32)  return ((const float*)p)[i];
    if (dt == DT_BF16) return __bfloat162float(((const hbf16*)p)[i]);
    return __half2float(((const __half*)p)[i]);
}
__device__ __forceinline__ void storeF(void* p, long i, int dt, float v) {
    if (dt == DT_F32)       ((float*)p)[i] = v;
    else if (dt == DT_BF16) ((hbf16*)p)[i] = __float2bfloat16(v);
    else                    ((__half*)p)[i] = __float2half(v);
}

// Vectorized 8-element load of any supported dtype (idx must be 8-elem aligned).
__device__ __forceinline__ void load8(const void* __restrict__ p, long idx, int dt, float* x) {
    if (dt == DT_F32) {
        const float4* f = (const float4*)((const float*)p + idx);
        float4 a = f[0], b = f[1];
        x[0]=a.x; x[1]=a.y; x[2]=a.z; x[3]=a.w;
        x[4]=b.x; x[5]=b.y; x[6]=b.z; x[7]=b.w;
    } else if (dt == DT_BF16) {
        bf16x8 v = *(const bf16x8*)((const __bf16*)p + idx);
        #pragma unroll
        for (int j = 0; j < 8; j++) x[j] = (float)v[j];
    } else {
        f16x8 v = *(const f16x8*)((const _Float16*)p + idx);
        #pragma unroll
        for (int j = 0; j < 8; j++) x[j] = (float)v[j];
    }
}
// Split f32 -> bf16 hi + bf16 lo (hi = RNE(x), lo = RNE(x - hi))
__device__ __forceinline__ void split8(const float* x, bf16x8& h, bf16x8& l) {
    #pragma unroll
    for (int j = 0; j < 8; j++) {
        float f = x[j];
        __bf16 hh = (__bf16)f;
        h[j] = hh;
        l[j] = (__bf16)(f - (float)hh);
    }
}
__device__ __forceinline__ void pack8f16(const float* x, f16x8& o) {
    #pragma unroll
    for (int j = 0; j < 8; j++) o[j] = (_Float16)x[j];
}

__device__ __forceinline__ f32x4 mfma16bf(bf16x8 a, bf16x8 b, f32x4 c) {
    return __builtin_amdgcn_mfma_f32_16x16x32_bf16(a, b, c, 0, 0, 0);
}
__device__ __forceinline__ f32x4 mfma16h(f16x8 a, f16x8 b, f32x4 c) {
    return __builtin_amdgcn_mfma_f32_16x16x32_f16(a, b, c, 0, 0, 0);
}

// ---------------------------------------------------------------------------
// setup: dtype + index-width detect, gather LUT map[n] = act[n>>8]*ROOM + (n&255)
__global__ void setup_kernel(const void* __restrict__ hidden_raw,
                             const void* __restrict__ act_raw,
                             int* __restrict__ map, int* __restrict__ flags)
{
    __shared__ int sh_mode, sh_is64;
    if (threadIdx.x == 0) {
        const unsigned int* w = (const unsigned int*)hidden_raw;
        int cnt = 0;
        for (int i = 0; i < 1024; i++) {
            int e = (w[i] >> 7) & 0xFF;
            if (e >= 110 && e <= 135) cnt++;
        }
        sh_mode = (cnt > 512) ? 1 : 0;
        const long long* a64 = (const long long*)act_raw;
        int ok = 1;
        for (int i = 0; i < 4; i++) {
            long long v = a64[i];
            if (v < 0 || v >= 8) { ok = 0; break; }
        }
        sh_is64 = ok;
        flags[0] = sh_mode;
        flags[1] = sh_is64;
    }
    __syncthreads();
    const int is64 = sh_is64;
    const int*       a32 = (const int*)act_raw;
    const long long* a64 = (const long long*)act_raw;
    for (int n = threadIdx.x; n < TD; n += blockDim.x) {
        int slot = n >> 8;
        int room = is64 ? (int)a64[slot] : a32[slot];
        map[n] = room * ROOM + (n & 255);
    }
}

// ---------------------------------------------------------------------------
// conv kernels: build operand planes from external inputs.
// f32 mode: bf16 hi + bf16 lo split pair. bf16 mode: single f16 plane (exact).
__global__ __launch_bounds__(256)
void conv_plain(const void* __restrict__ src, __bf16* __restrict__ hi,
                __bf16* __restrict__ lo, const int* __restrict__ flags)
{
    const int mode = flags[0];
    const int dt = resolveDT(SEL_IN, mode);
    const long i = ((long)blockIdx.x * 256 + threadIdx.x) * 8;
    float x[8]; load8(src, i, dt, x);
    if (mode == 1) {
        f16x8 h; pack8f16(x, h);
        *(f16x8*)((_Float16*)hi + i) = h;
    } else {
        bf16x8 h, l; split8(x, h, l);
        *(bf16x8*)(hi + i) = h;
        *(bf16x8*)(lo + i) = l;
    }
}

// rows gathered through map: dst[n][*] = src[map[n]][*]    (row length H_)
__global__ __launch_bounds__(256)
void conv_gather(const void* __restrict__ src, __bf16* __restrict__ hi,
                 __bf16* __restrict__ lo, const int* __restrict__ map,
                 const int* __restrict__ flags)
{
    const int mode = flags[0];
    const int dt = resolveDT(SEL_IN, mode);
    const int n = blockIdx.x;
    const long c = (long)threadIdx.x * 8;
    float x[8]; load8(src, (long)map[n] * H_ + c, dt, x);
    const long o = (long)n * H_ + c;
    if (mode == 1) {
        f16x8 h; pack8f16(x, h);
        *(f16x8*)((_Float16*)hi + o) = h;
    } else {
        bf16x8 h, l; split8(x, h, l);
        *(bf16x8*)(hi + o) = h;
        *(bf16x8*)(lo + o) = l;
    }
}

// gather + transpose: oT[h][t] = o_block[map[t]][h]   (LDS-tiled 64x64)
__global__ __launch_bounds__(256)
void conv_gatherT(const void* __restrict__ src, __bf16* __restrict__ hi,
                  __bf16* __restrict__ lo, const int* __restrict__ map,
                  const int* __restrict__ flags)
{
    const int mode = flags[0];
    const int dt = resolveDT(SEL_IN, mode);
    const int tB = blockIdx.x * 64;   // t-dim (gathered source rows / dest cols)
    const int hB = blockIdx.y * 64;   // h-dim (source cols / dest rows)
    __shared__ float Ts[64][65];
    const int tid = threadIdx.x;
    const int i  = tid >> 2;          // 0..63
    const int j0 = (tid & 3) * 16;
    {
        const int srow = map[tB + i];
        const long base = (long)srow * H_ + hB + j0;
        float x[16];
        load8(src, base, dt, x);
        load8(src, base + 8, dt, x + 8);
        #pragma unroll
        for (int j = 0; j < 16; j++) Ts[i][j0 + j] = x[j];
    }
    __syncthreads();
    {
        const long drow = (long)(hB + i) * TD + tB + j0;
        float y[16];
        #pragma unroll
        for (int j = 0; j < 16; j++) y[j] = Ts[j0 + j][i];
        if (mode == 1) {
            f16x8 h0, h1;
            pack8f16(y, h0); pack8f16(y + 8, h1);
            *(f16x8*)((_Float16*)hi + drow)     = h0;
            *(f16x8*)((_Float16*)hi + drow + 8) = h1;
        } else {
            bf16x8 h0, h1, l0, l1;
            split8(y, h0, l0);
            split8(y + 8, h1, l1);
            *(bf16x8*)(hi + drow)     = h0;
            *(bf16x8*)(hi + drow + 8) = h1;
            *(bf16x8*)(lo + drow)     = l0;
            *(bf16x8*)(lo + drow + 8) = l1;
        }
    }
}

// ---------------------------------------------------------------------------
// MFMA GEMM:  C[m][n] = scale * sum_k A[m][k]*B[n][k]
// f32 mode: split-bf16 3-pass; bf16 mode: 1-pass f16 on single planes.
// Epilogue v2: stage C tile in (reused) LDS, flush with 16B/lane vector stores
// instead of 2-byte scalar stores at stride-16 (the round-5 bottleneck theory).
#define BN 128
#define BK 32
#define KST 40    // padded LDS k-stride (16B-aligned rows, conflict-spread)
#define EPAD 136  // epilogue LDS row stride in 2B elems (=272B, 16B-aligned, bank-spread)
#define EPAD4 68  // epilogue LDS row stride in f32 elems (=272B)

template<int TBM, int AMODE, int EPI, bool CAUSAL>
__global__ __launch_bounds__(256)
void mgemm(const __bf16* __restrict__ Ah, const __bf16* __restrict__ Al,
           const void* __restrict__ Araw, int aSel,
           const __bf16* __restrict__ Bh, const __bf16* __restrict__ Bl,
           __bf16* __restrict__ Ch, __bf16* __restrict__ Cl,
           void* __restrict__ Craw, int cSel,
           int K, int lda, int ldb, int ldc,
           long aBase, long bBase, long cBase,
           long aZ, long bZ, int bMod2, long cZ,
           const int* __restrict__ flags, int aLoSel, int bLoSel,
           float scale, float maskval)
{
    constexpr int NI = 4;                      // 64 rows per wave
    constexpr int NJ = (TBM == 128) ? 4 : 2;   // wave N-frags
    constexpr int ASZ = 2 * TBM * KST;         // bf16 elems
    constexpr int BSZ = 2 * BN * KST;

    const int mode = flags[0];
    const bool f16m = (mode == 1);             // single-pass f16 pipeline
    const bool useALo = (aLoSel == 0) || (mode == 0);
    const bool useBLo = (bLoSel == 0) || (mode == 0);
    const int aDT = (AMODE == 1) ? resolveDT(aSel, mode) : DT_F32;

    const int z = blockIdx.z;
    const long aOff = aBase + (long)z * aZ;
    const long bOff = bBase + (bMod2 ? (long)(z & 1) * bZ : (long)z * bZ);
    const long cOff = cBase + (long)z * cZ;

    // XCD-bijective swizzle of the (x,y) tile index (8 XCDs on MI355X)
    const int gx = gridDim.x;
    const int nwg = gx * gridDim.y;
    const int orig = blockIdx.y * gx + blockIdx.x;
    const int q8 = nwg >> 3, r8 = nwg & 7;
    const int xcd = orig & 7, off8 = orig >> 3;
    const int wg = (xcd < r8 ? xcd * (q8 + 1) : r8 * (q8 + 1) + (xcd - r8) * q8) + off8;
    const int rowBase = (wg / gx) * TBM;
    const int colBase = (wg % gx) * BN;

    // single shared pool: staging (As|Bs) during K-loop, C-tile in epilogue
    __shared__ __align__(16) __bf16 smem[ASZ + BSZ];
    auto As = (__bf16 (*)[TBM][KST])smem;          // As[buf][r][c]
    auto Bs = (__bf16 (*)[BN][KST])(smem + ASZ);   // Bs[buf][r][c]

    const int tid  = threadIdx.x;
    const int lane = tid & 63;
    const int w    = tid >> 6;
    const int fr   = lane & 15;   // frag row/col within 16
    const int fq   = lane >> 4;   // k-group (inputs) / row-group (C)

    // wave output sub-tile origin
    const int rowW = (TBM == 128) ? (w >> 1) * 64 : 0;
    const int colW = (TBM == 128) ? (w & 1) * 64  : w * 32;

    // staging assignments
    const int sAr = (TBM == 128) ? (tid >> 1) : (tid >> 2);
    const int sAc = (TBM == 128) ? (tid & 1) * 16 : (tid & 3) * 8;
    const int sBr = tid >> 1;
    const int sBc = (tid & 1) * 16;

    f32x4 acc[NI][NJ];
    const f32x4 zero = {0.f, 0.f, 0.f, 0.f};
    #pragma unroll
    for (int i = 0; i < NI; i++)
        #pragma unroll
        for (int j = 0; j < NJ; j++) acc[i][j] = zero;

    // prefetch registers
    bf16x8 pA0, pA1, pA2, pA3;     // plane0 x2, plane1 x2 (TBM=64: pA0/pA2 only)
    float  pAf[16];                // AMODE1 raw f32 (TBM=64 uses [0..7])
    bf16x8 pB0, pB1, pB2, pB3;

    auto issueA = [&](int kt) {
        const long e = aOff + (long)(rowBase + sAr) * lda + kt + sAc;
        if constexpr (AMODE == 0) {
            if constexpr (TBM == 128) {
                pA0 = *(const bf16x8*)(Ah + e);
                pA1 = *(const bf16x8*)(Ah + e + 8);
                if (!f16m) {
                    pA2 = *(const bf16x8*)(Al + e);
                    pA3 = *(const bf16x8*)(Al + e + 8);
                }
            } else {
                pA0 = *(const bf16x8*)(Ah + e);
                if (!f16m) pA2 = *(const bf16x8*)(Al + e);
            }
        } else {
            if constexpr (TBM == 128) {
                load8(Araw, e, aDT, pAf);
                load8(Araw, e + 8, aDT, pAf + 8);
            } else {
                load8(Araw, e, aDT, pAf);
            }
        }
    };
    auto issueB = [&](int kt) {
        const long e = bOff + (long)(colBase + sBr) * ldb + kt + sBc;
        pB0 = *(const bf16x8*)(Bh + e);
        pB1 = *(const bf16x8*)(Bh + e + 8);
        if (!f16m) {
            pB2 = *(const bf16x8*)(Bl + e);
            pB3 = *(const bf16x8*)(Bl + e + 8);
        }
    };
    auto commit = [&]() {
        if constexpr (AMODE == 0) {
            if constexpr (TBM == 128) {
                *(bf16x8*)&As[0][sAr][sAc]     = pA0;
                *(bf16x8*)&As[0][sAr][sAc + 8] = pA1;
                if (!f16m) {
                    *(bf16x8*)&As[1][sAr][sAc]     = pA2;
                    *(bf16x8*)&As[1][sAr][sAc + 8] = pA3;
                }
            } else {
                *(bf16x8*)&As[0][sAr][sAc] = pA0;
                if (!f16m) *(bf16x8*)&As[1][sAr][sAc] = pA2;
            }
        } else {
            if (f16m) {
                if constexpr (TBM == 128) {
                    f16x8 h0, h1;
                    pack8f16(pAf, h0); pack8f16(pAf + 8, h1);
                    *(f16x8*)&As[0][sAr][sAc]     = h0;
                    *(f16x8*)&As[0][sAr][sAc + 8] = h1;
                } else {
                    f16x8 h0; pack8f16(pAf, h0);
                    *(f16x8*)&As[0][sAr][sAc] = h0;
                }
            } else {
                if constexpr (TBM == 128) {
                    bf16x8 h0, h1, l0, l1;
                    split8(pAf, h0, l0);
                    split8(pAf + 8, h1, l1);
                    *(bf16x8*)&As[0][sAr][sAc]     = h0;
                    *(bf16x8*)&As[0][sAr][sAc + 8] = h1;
                    *(bf16x8*)&As[1][sAr][sAc]     = l0;
                    *(bf16x8*)&As[1][sAr][sAc + 8] = l1;
                } else {
                    bf16x8 h0, l0;
                    split8(pAf, h0, l0);
                    *(bf16x8*)&As[0][sAr][sAc] = h0;
                    *(bf16x8*)&As[1][sAr][sAc] = l0;
                }
            }
        }
        *(bf16x8*)&Bs[0][sBr][sBc]     = pB0;
        *(bf16x8*)&Bs[0][sBr][sBc + 8] = pB1;
        if (!f16m) {
            *(bf16x8*)&Bs[1][sBr][sBc]     = pB2;
            *(bf16x8*)&Bs[1][sBr][sBc + 8] = pB3;
        }
    };

    issueA(0); issueB(0);

    for (int kt = 0; kt < K; kt += BK) {
        commit();                       // vmcnt waits auto-inserted on reg use
        __syncthreads();                // LDS tile visible to all waves
        if (kt + BK < K) {              // issue next tile's loads EARLY
            issueA(kt + BK);
            issueB(kt + BK);
        }
        __builtin_amdgcn_sched_barrier(0);  // pin load-issue above compute

        if (f16m) {
            f16x8 a16[NI], b16[NJ];
            #pragma unroll
            for (int i = 0; i < NI; i++)
                a16[i] = *(const f16x8*)&As[0][rowW + i * 16 + fr][fq * 8];
            #pragma unroll
            for (int j = 0; j < NJ; j++)
                b16[j] = *(const f16x8*)&Bs[0][colW + j * 16 + fr][fq * 8];
            #pragma unroll
            for (int i = 0; i < NI; i++)
                #pragma unroll
                for (int j = 0; j < NJ; j++)
                    acc[i][j] = mfma16h(a16[i], b16[j], acc[i][j]);
        } else {
            bf16x8 ah[NI], al[NI], bh[NJ], bl[NJ];
            #pragma unroll
            for (int i = 0; i < NI; i++)
                ah[i] = *(const bf16x8*)&As[0][rowW + i * 16 + fr][fq * 8];
            #pragma unroll
            for (int j = 0; j < NJ; j++)
                bh[j] = *(const bf16x8*)&Bs[0][colW + j * 16 + fr][fq * 8];
            if (useALo)
                #pragma unroll
                for (int i = 0; i < NI; i++)
                    al[i] = *(const bf16x8*)&As[1][rowW + i * 16 + fr][fq * 8];
            if (useBLo)
                #pragma unroll
                for (int j = 0; j < NJ; j++)
                    bl[j] = *(const bf16x8*)&Bs[1][colW + j * 16 + fr][fq * 8];

            #pragma unroll
            for (int i = 0; i < NI; i++)
                #pragma unroll
                for (int j = 0; j < NJ; j++)
                    acc[i][j] = mfma16bf(ah[i], bh[j], acc[i][j]);
            if (useBLo)
                #pragma unroll
                for (int i = 0; i < NI; i++)
                    #pragma unroll
                    for (int j = 0; j < NJ; j++)
                        acc[i][j] = mfma16bf(ah[i], bl[j], acc[i][j]);
            if (useALo)
                #pragma unroll
                for (int i = 0; i < NI; i++)
                    #pragma unroll
                    for (int j = 0; j < NJ; j++)
                        acc[i][j] = mfma16bf(al[i], bh[j], acc[i][j]);
        }
        __syncthreads();                // all reads done before next commit
    }

    // ---- epilogue v2: LDS-staged, vector-flushed ---------------------------
    // C/D frag layout: lane holds col = colW + j*16 + (lane&15), rows fq*4+rr.
    const int cDT = (EPI == 0) ? (f16m ? DT_F16 : DT_BF16) : resolveDT(cSel, mode);
    // (K-loop's final __syncthreads() makes staging LDS reusable here)

    if (EPI == 1 && cDT == DT_F32) {
        // f32 target: two column-half passes through LDS [TBM][EPAD4]
        float* ep = (float*)smem;
        #pragma unroll
        for (int half = 0; half < 2; half++) {
            if ((colW >> 6) == half) {
                #pragma unroll
                for (int i = 0; i < NI; i++)
                    #pragma unroll
                    for (int rr = 0; rr < 4; rr++) {
                        const int lrow = rowW + i * 16 + fq * 4 + rr;
                        #pragma unroll
                        for (int j = 0; j < NJ; j++) {
                            float v = acc[i][j][rr] * scale;
                            const int lcol = colW + j * 16 + fr;
                            if (CAUSAL) {
                                if (colBase + lcol > rowBase + lrow) v = maskval;
                            }
                            ep[lrow * EPAD4 + (lcol - half * 64)] = v;
                        }
                    }
            }
            __syncthreads();
            const int chunk = tid & 15, r0 = tid >> 4;
            for (int r = r0; r < TBM; r += 16) {
                float4 v = *(const float4*)&ep[(long)r * EPAD4 + chunk * 4];
                *(float4*)((float*)Craw + cOff + (long)(rowBase + r) * ldc
                           + colBase + half * 64 + chunk * 4) = v;
            }
            __syncthreads();
        }
    } else {
        // 2-byte targets: full-width tile [TBM][EPAD], one round per plane
        const int planes = (EPI == 0 && !f16m) ? 2 : 1;
        for (int pl = 0; pl < planes; pl++) {
            #pragma unroll
            for (int i = 0; i < NI; i++)
                #pragma unroll
                for (int rr = 0; rr < 4; rr++) {
                    const int lrow = rowW + i * 16 + fq * 4 + rr;
                    #pragma unroll
                    for (int j = 0; j < NJ; j++) {
                        float v = acc[i][j][rr];
                        const int lcol = colW + j * 16 + fr;
                        if constexpr (EPI == 1) {
                            v *= scale;
                            if (CAUSAL) {
                                if (colBase + lcol > rowBase + lrow) v = maskval;
                            }
                        }
                        const long li = (long)lrow * EPAD + lcol;
                        if (cDT == DT_F16) {
                            ((_Float16*)smem)[li] = (_Float16)v;
                        } else {
                            __bf16 h = (__bf16)v;
                            ((__bf16*)smem)[li] = (pl == 0) ? h : (__bf16)(v - (float)h);
                        }
                    }
                }
            __syncthreads();
            __bf16* dst = (EPI == 1) ? (__bf16*)Craw : (pl == 0 ? Ch : Cl);
            const int chunk = tid & 15, r0 = tid >> 4;
            for (int r = r0; r < TBM; r += 16) {
                bf16x8 v = *(const bf16x8*)((const __bf16*)smem + (long)r * EPAD + chunk * 8);
                *(bf16x8*)(dst + cOff + (long)(rowBase + r) * ldc + colBase + chunk * 8) = v;
            }
            __syncthreads();
        }
    }
}

// ---------------------------------------------------------------------------
// In-place row softmax over attn region (reads SEL_SCORE, writes SEL_OUT)
__global__ __launch_bounds__(256)
void softmax_kernel(void* __restrict__ attn, long base, const int* __restrict__ flags)
{
    const int mode  = flags[0];
    const int rdDT  = resolveDT(SEL_SCORE, mode);
    const int wrDT  = resolveDT(SEL_OUT, mode);

    const int qrow = blockIdx.x;
    const int h    = blockIdx.y;
    const long row = base + ((long)h * S_ + qrow) * S_;
    const int tid  = threadIdx.x;
    const int wave = tid >> 6, lane = tid & 63;

    float vals[8];
    const bool v32 = (rdDT == DT_F32);   // f32 mode: float4 fast path
    const bool v16 = (rdDT == DT_F16);   // bf16 mode: f16x8 read / bf16x8 write
    const long my8 = row + (long)tid * 8;
    if (v16) {
        f16x8 v = *(const f16x8*)((const _Float16*)attn + my8);
        #pragma unroll
        for (int j = 0; j < 8; j++) vals[j] = (float)v[j];
    } else if (v32) {
        const float4* rp = (const float4*)((const float*)attn + row);
        float4 a = rp[tid], b = rp[tid + 256];
        vals[0]=a.x; vals[1]=a.y; vals[2]=a.z; vals[3]=a.w;
        vals[4]=b.x; vals[5]=b.y; vals[6]=b.z; vals[7]=b.w;
    } else {
        #pragma unroll
        for (int i = 0; i < 8; i++)
            vals[i] = loadF(attn, row + tid + i * 256, rdDT);
    }

    float m = -3.4e38f;
    #pragma unroll
    for (int i = 0; i < 8; i++) m = fmaxf(m, vals[i]);
    #pragma unroll
    for (int off = 32; off > 0; off >>= 1)
        m = fmaxf(m, __shfl_down(m, off, 64));
    __shared__ float redm[4];
    if (lane == 0) redm[wave] = m;
    __syncthreads();
    if (tid == 0) redm[0] = fmaxf(fmaxf(redm[0], redm[1]), fmaxf(redm[2], redm[3]));
    __syncthreads();
    m = redm[0];

    float s = 0.f;
    #pragma unroll
    for (int i = 0; i < 8; i++) {
        vals[i] = __expf(vals[i] - m);
        s += vals[i];
    }
    #pragma unroll
    for (int off = 32; off > 0; off >>= 1)
        s += __shfl_down(s, off, 64);
    __shared__ float reds[4];
    if (lane == 0) reds[wave] = s;
    __syncthreads();
    if (tid == 0) reds[0] = reds[0] + reds[1] + reds[2] + reds[3];
    __syncthreads();
    const float inv = 1.f / reds[0];

    if (v16 && wrDT == DT_BF16) {
        bf16x8 o;
        #pragma unroll
        for (int j = 0; j < 8; j++) o[j] = (__bf16)(vals[j] * inv);
        *(bf16x8*)((__bf16*)attn + my8) = o;
    } else if (v32 && wrDT == DT_F32) {
        float4* wp = (float4*)((float*)attn + row);
        float4 a, b;
        a.x=vals[0]*inv; a.y=vals[1]*inv; a.z=vals[2]*inv; a.w=vals[3]*inv;
        b.x=vals[4]*inv; b.y=vals[5]*inv; b.z=vals[6]*inv; b.w=vals[7]*inv;
        wp[tid] = a; wp[tid + 256] = b;
    } else {
        #pragma unroll
        for (int i = 0; i < 8; i++)
            storeF(attn, row + tid + i * 256, wrDT, vals[i] * inv);
    }
}

// ---------------------------------------------------------------------------
extern "C" void kernel_launch(void* const* d_in, const int* in_sizes, int n_in,
                              void* d_out, int out_size, void* d_ws, size_t ws_size,
                              hipStream_t stream)
{
    (void)in_sizes; (void)n_in; (void)out_size; (void)ws_size;

    const void* hidden = d_in[0];
    const void* qb     = d_in[1];
    const void* kb     = d_in[2];
    const void* vb     = d_in[3];
    const void* ob     = d_in[4];
    const void* act    = d_in[5];

    const long ATTN_BASE = (long)S_ * TD;

    // Workspace: operand planes (~59 MB), with buffer reuse across phases
    const long PLANE = (long)S_ * H_;        // 4M elems
    const long SMALL = (long)ROOM * H_;      // 0.5M elems
    __bf16* p = (__bf16*)d_ws;
    __bf16* hidH = p;               __bf16* hidL = hidH + PLANE;  // hidden planes
    __bf16* aoH  = hidH;            __bf16* aoL  = hidL;          // reuse: attn_out planes
    __bf16* qbH  = p + 2 * PLANE;   __bf16* qbL  = qbH + PLANE;   // gathered q_block planes
    __bf16* otH  = qbH;             __bf16* otL  = qbL;           // reuse: o_block^T planes
    __bf16* qfH  = p + 4 * PLANE;   __bf16* qfL  = qfH + PLANE;   // qf planes [S][TD]
    __bf16* kbH  = p + 6 * PLANE;   __bf16* kbL  = kbH + SMALL;   // k_block planes
    __bf16* vbH  = kbL + SMALL;     __bf16* vbL  = vbH + SMALL;   // v_block planes
    __bf16* k1H  = vbL + SMALL;     __bf16* k1L  = k1H + SMALL;   // k_one planes [S][ROOM]
    __bf16* vtH  = k1L + SMALL;     __bf16* vtL  = vtH + SMALL;   // v_one^T planes [ROOM][S]
    int* map   = (int*)(vtL + SMALL);
    int* flags = map + TD;

    const float inv_sqrt_hd = 0.08838834764831845f;

    setup_kernel<<<1, 256, 0, stream>>>(hidden, act, map, flags);

    // input -> plane conversions
    conv_plain<<<dim3((unsigned)(PLANE / 2048)), 256, 0, stream>>>(hidden, hidH, hidL, flags);
    conv_gather<<<dim3(TD), 256, 0, stream>>>(qb, qbH, qbL, map, flags);
    conv_plain<<<dim3((unsigned)(SMALL / 2048)), 256, 0, stream>>>(kb, kbH, kbL, flags);
    conv_plain<<<dim3((unsigned)(SMALL / 2048)), 256, 0, stream>>>(vb, vbH, vbL, flags);

    // G1: qf = hidden x qB^T          M=S, N=TD, K=H      (512 blocks, 2/CU)
    mgemm<64, 0, 0, false><<<dim3(TD / BN, S_ / 64, 1), 256, 0, stream>>>(
        hidH, hidL, nullptr, 0, qbH, qbL, qfH, qfL, nullptr, 0,
        H_, H_, H_, TD, 0, 0, 0, 0, 0, 0, 0, flags, 1, 1, 1.f, 0.f);

    // G2: k_one = hidden x kB^T       M=S, N=ROOM, K=H
    mgemm<64, 0, 0, false><<<dim3(ROOM / BN, S_ / 64, 1), 256, 0, stream>>>(
        hidH, hidL, nullptr, 0, kbH, kbL, k1H, k1L, nullptr, 0,
        H_, H_, H_, ROOM, 0, 0, 0, 0, 0, 0, 0, flags, 1, 1, 1.f, 0.f);

    // G3: v_one^T = v_block x hidden^T   M=ROOM, N=S, K=H  (transposed for free)
    mgemm<64, 0, 0, false><<<dim3(S_ / BN, ROOM / 64, 1), 256, 0, stream>>>(
        vbH, vbL, nullptr, 0, hidH, hidL, vtH, vtL, nullptr, 0,
        H_, H_, H_, S_, 0, 0, 0, 0, 0, 0, 0, flags, 1, 1, 1.f, 0.f);

    // G4: raw causal scores per head -> d_out attn region   K=HD
    mgemm<128, 0, 1, true><<<dim3(S_ / BN, S_ / 128, NH), 256, 0, stream>>>(
        qfH, qfL, nullptr, 0, k1H, k1L, nullptr, nullptr, d_out, SEL_SCORE,
        HD, TD, ROOM, S_, 0, 0, ATTN_BASE,
        (long)HD, (long)HD, 1, (long)S_ * S_, flags, 0, 0, inv_sqrt_hd, -1e4f);

    // G5: softmax in-place (graded attention weights)
    softmax_kernel<<<dim3(S_, NH), 256, 0, stream>>>(d_out, ATTN_BASE, flags);

    // o_block gather+transpose planes (qB buffer is dead now)
    conv_gatherT<<<dim3(TD / 64, H_ / 64), 256, 0, stream>>>(ob, otH, otL, map, flags);

    // G6: attn_out = P x v_one^T^T    per head: M=S, N=HD, K=S  (512 blocks)
    //     A read+convert on the fly from graded weights in d_out
    mgemm<64, 1, 0, false><<<dim3(HD / BN, S_ / 64, NH), 256, 0, stream>>>(
        nullptr, nullptr, d_out, SEL_OUT, vtH, vtL, aoH, aoL, nullptr, 0,
        S_, S_, S_, TD, ATTN_BASE, 0, 0,
        (long)S_ * S_, (long)HD * S_, 1, (long)HD, flags, 1, 0, 1.f, 0.f);

    // G7: o_out = attn_out x oT^T     M=S, N=H, K=TD      (512 blocks, 2/CU)
    mgemm<64, 0, 1, false><<<dim3(H_ / BN, S_ / 64, 1), 256, 0, stream>>>(
        aoH, aoL, nullptr, 0, otH, otL, nullptr, nullptr, d_out, SEL_OUT,
        TD, TD, TD, H_, 0, 0, 0, 0, 0, 0, 0, flags, 0, 1, 1.f, 0.f);
}

// Round 8
// 786.280 us; speedup vs baseline: 1.1156x; 1.1156x over previous
//
#include <hip/hip_runtime.h>
#include <hip/hip_bf16.h>
#include <hip/hip_fp16.h>

// Problem constants (fixed by setup_inputs)
#define S_   2048
#define H_   2048
#define ROOM 256
#define NH   16
#define HD   128   // head_dim
#define TD   2048  // total_dim

typedef __hip_bfloat16 hbf16;

// Runtime dtype codes
#define DT_F32  0
#define DT_BF16 1
#define DT_F16  2
// Operand selectors (resolved against detected mode)
#define SEL_F32   0
#define SEL_IN    1   // f32-mode: f32 ; bf16-mode: bf16
#define SEL_SCORE 2   // f32-mode: f32 ; bf16-mode: f16
#define SEL_OUT   3   // f32-mode: f32 ; bf16-mode: bf16

typedef __bf16    bf16x8 __attribute__((ext_vector_type(8)));
typedef _Float16  f16x8  __attribute__((ext_vector_type(8)));
typedef float     f32x4  __attribute__((ext_vector_type(4)));

__device__ __forceinline__ int resolveDT(int sel, int bf16mode) {
    if (sel == SEL_F32) return DT_F32;
    if (sel == SEL_SCORE) return bf16mode ? DT_F16 : DT_F32;
    return bf16mode ? DT_BF16 : DT_F32;
}
__device__ __forceinline__ float loadF(const void* p, long i, int dt) {
    if (dt == DT_F32)  return ((const float*)p)[i];
    if (dt == DT_BF16) return __bfloat162float(((const hbf16*)p)[i]);
    return __half2float(((const __half*)p)[i]);
}
__device__ __forceinline__ void storeF(void* p, long i, int dt, float v) {
    if (dt == DT_F32)       ((float*)p)[i] = v;
    else if (dt == DT_BF16) ((hbf16*)p)[i] = __float2bfloat16(v);
    else                    ((__half*)p)[i] = __float2half(v);
}

// Vectorized 8-element load of any supported dtype (idx must be 8-elem aligned).
__device__ __forceinline__ void load8(const void* __restrict__ p, long idx, int dt, float* x) {
    if (dt == DT_F32) {
        const float4* f = (const float4*)((const float*)p + idx);
        float4 a = f[0], b = f[1];
        x[0]=a.x; x[1]=a.y; x[2]=a.z; x[3]=a.w;
        x[4]=b.x; x[5]=b.y; x[6]=b.z; x[7]=b.w;
    } else if (dt == DT_BF16) {
        bf16x8 v = *(const bf16x8*)((const __bf16*)p + idx);
        #pragma unroll
        for (int j = 0; j < 8; j++) x[j] = (float)v[j];
    } else {
        f16x8 v = *(const f16x8*)((const _Float16*)p + idx);
        #pragma unroll
        for (int j = 0; j < 8; j++) x[j] = (float)v[j];
    }
}
// Split f32 -> bf16 hi + bf16 lo (hi = RNE(x), lo = RNE(x - hi))
__device__ __forceinline__ void split8(const float* x, bf16x8& h, bf16x8& l) {
    #pragma unroll
    for (int j = 0; j < 8; j++) {
        float f = x[j];
        __bf16 hh = (__bf16)f;
        h[j] = hh;
        l[j] = (__bf16)(f - (float)hh);
    }
}
__device__ __forceinline__ void pack8f16(const float* x, f16x8& o) {
    #pragma unroll
    for (int j = 0; j < 8; j++) o[j] = (_Float16)x[j];
}

__device__ __forceinline__ f32x4 mfma16bf(bf16x8 a, bf16x8 b, f32x4 c) {
    return __builtin_amdgcn_mfma_f32_16x16x32_bf16(a, b, c, 0, 0, 0);
}
__device__ __forceinline__ f32x4 mfma16h(f16x8 a, f16x8 b, f32x4 c) {
    return __builtin_amdgcn_mfma_f32_16x16x32_f16(a, b, c, 0, 0, 0);
}

// ---------------------------------------------------------------------------
// setup: dtype + index-width detect (parallelized), gather LUT
__global__ void setup_kernel(const void* __restrict__ hidden_raw,
                             const void* __restrict__ act_raw,
                             int* __restrict__ map, int* __restrict__ flags)
{
    __shared__ int sh_cnt, sh_is64;
    const int tid = threadIdx.x;
    if (tid == 0) {
        sh_cnt = 0;
        const long long* a64 = (const long long*)act_raw;
        int ok = 1;
        for (int i = 0; i < 4; i++) {
            long long v = a64[i];
            if (v < 0 || v >= 8) { ok = 0; break; }
        }
        sh_is64 = ok;
    }
    __syncthreads();
    {
        const unsigned int* w = (const unsigned int*)hidden_raw;
        int local = 0;
        for (int i = tid; i < 1024; i += 256) {
            int e = (w[i] >> 7) & 0xFF;
            if (e >= 110 && e <= 135) local++;
        }
        atomicAdd(&sh_cnt, local);
    }
    __syncthreads();
    if (tid == 0) {
        flags[0] = (sh_cnt > 512) ? 1 : 0;
        flags[1] = sh_is64;
    }
    const int is64 = sh_is64;
    const int*       a32 = (const int*)act_raw;
    const long long* a64 = (const long long*)act_raw;
    for (int n = tid; n < TD; n += blockDim.x) {
        int slot = n >> 8;
        int room = is64 ? (int)a64[slot] : a32[slot];
        map[n] = room * ROOM + (n & 255);
    }
}

// ---------------------------------------------------------------------------
// conv kernels: build operand planes from external inputs.
// f32 mode: bf16 hi + bf16 lo split pair. bf16 mode: single f16 plane (exact).
__global__ __launch_bounds__(256)
void conv_plain(const void* __restrict__ src, __bf16* __restrict__ hi,
                __bf16* __restrict__ lo, const int* __restrict__ flags)
{
    const int mode = flags[0];
    const int dt = resolveDT(SEL_IN, mode);
    const long i = ((long)blockIdx.x * 256 + threadIdx.x) * 8;
    float x[8]; load8(src, i, dt, x);
    if (mode == 1) {
        f16x8 h; pack8f16(x, h);
        *(f16x8*)((_Float16*)hi + i) = h;
    } else {
        bf16x8 h, l; split8(x, h, l);
        *(bf16x8*)(hi + i) = h;
        *(bf16x8*)(lo + i) = l;
    }
}

// rows gathered through map: dst[n][*] = src[map[n]][*]    (row length H_)
__global__ __launch_bounds__(256)
void conv_gather(const void* __restrict__ src, __bf16* __restrict__ hi,
                 __bf16* __restrict__ lo, const int* __restrict__ map,
                 const int* __restrict__ flags)
{
    const int mode = flags[0];
    const int dt = resolveDT(SEL_IN, mode);
    const int n = blockIdx.x;
    const long c = (long)threadIdx.x * 8;
    float x[8]; load8(src, (long)map[n] * H_ + c, dt, x);
    const long o = (long)n * H_ + c;
    if (mode == 1) {
        f16x8 h; pack8f16(x, h);
        *(f16x8*)((_Float16*)hi + o) = h;
    } else {
        bf16x8 h, l; split8(x, h, l);
        *(bf16x8*)(hi + o) = h;
        *(bf16x8*)(lo + o) = l;
    }
}

// gather + transpose: oT[h][t] = o_block[map[t]][h]   (LDS-tiled 64x64)
__global__ __launch_bounds__(256)
void conv_gatherT(const void* __restrict__ src, __bf16* __restrict__ hi,
                  __bf16* __restrict__ lo, const int* __restrict__ map,
                  const int* __restrict__ flags)
{
    const int mode = flags[0];
    const int dt = resolveDT(SEL_IN, mode);
    const int tB = blockIdx.x * 64;   // t-dim (gathered source rows / dest cols)
    const int hB = blockIdx.y * 64;   // h-dim (source cols / dest rows)
    __shared__ float Ts[64][65];
    const int tid = threadIdx.x;
    const int i  = tid >> 2;          // 0..63
    const int j0 = (tid & 3) * 16;
    {
        const int srow = map[tB + i];
        const long base = (long)srow * H_ + hB + j0;
        float x[16];
        load8(src, base, dt, x);
        load8(src, base + 8, dt, x + 8);
        #pragma unroll
        for (int j = 0; j < 16; j++) Ts[i][j0 + j] = x[j];
    }
    __syncthreads();
    {
        const long drow = (long)(hB + i) * TD + tB + j0;
        float y[16];
        #pragma unroll
        for (int j = 0; j < 16; j++) y[j] = Ts[j0 + j][i];
        if (mode == 1) {
            f16x8 h0, h1;
            pack8f16(y, h0); pack8f16(y + 8, h1);
            *(f16x8*)((_Float16*)hi + drow)     = h0;
            *(f16x8*)((_Float16*)hi + drow + 8) = h1;
        } else {
            bf16x8 h0, h1, l0, l1;
            split8(y, h0, l0);
            split8(y + 8, h1, l1);
            *(bf16x8*)(hi + drow)     = h0;
            *(bf16x8*)(hi + drow + 8) = h1;
            *(bf16x8*)(lo + drow)     = l0;
            *(bf16x8*)(lo + drow + 8) = l1;
        }
    }
}

// ---------------------------------------------------------------------------
// MFMA GEMM:  C[m][n] = scale * sum_k A[m][k]*B[n][k]
// BK=64. f16 mode (runtime): single-pass f16 MFMA, double-buffered LDS,
//   ONE barrier per K-step (issue(t+1) -> ds_read+MFMA(t) -> commit(t+1,alt) -> bar).
// f32 mode: split-bf16 3-pass, plane-pair LDS, 2 barriers/step (legacy path).
// Epilogue: LDS-staged, 16B/lane vector flush.
#define BN 128
#define BK 64
#define KSTP 72   // padded LDS k-stride (16B-aligned rows, conflict-spread)
#define EPAD 136  // epilogue LDS row stride in 2B elems
#define EPAD4 68  // epilogue LDS row stride in f32 elems

template<int TBM, int AMODE, int EPI, bool CAUSAL>
__global__ __launch_bounds__(256)
void mgemm(const __bf16* __restrict__ Ah, const __bf16* __restrict__ Al,
           const void* __restrict__ Araw, int aSel,
           const __bf16* __restrict__ Bh, const __bf16* __restrict__ Bl,
           __bf16* __restrict__ Ch, __bf16* __restrict__ Cl,
           void* __restrict__ Craw, int cSel,
           int K, int lda, int ldb, int ldc,
           long aBase, long bBase, long cBase,
           long aZ, long bZ, int bMod2, long cZ,
           const int* __restrict__ flags, int aLoSel, int bLoSel,
           float scale, float maskval)
{
    constexpr int NI = 4;                      // 64 rows per wave
    constexpr int NJ = (TBM == 128) ? 4 : 2;   // wave N-frags
    constexpr int AE = TBM / 32;               // A staging vectors/thread (2 or 4)
    constexpr int BE = 4;                      // B staging vectors/thread
    constexpr int ASZ = 2 * TBM * KSTP;        // bf16 elems (2 bufs or 2 planes)
    constexpr int BSZ = 2 * BN * KSTP;

    const int mode = flags[0];
    const bool f16m = (mode == 1);
    const bool useALo = (aLoSel == 0) || (mode == 0);
    const bool useBLo = (bLoSel == 0) || (mode == 0);
    const int aDT = (AMODE == 1) ? resolveDT(aSel, mode) : DT_F32;

    const int z = blockIdx.z;
    const long aOff = aBase + (long)z * aZ;
    const long bOff = bBase + (bMod2 ? (long)(z & 1) * bZ : (long)z * bZ);
    const long cOff = cBase + (long)z * cZ;

    // XCD-bijective swizzle of the (x,y) tile index (8 XCDs on MI355X)
    const int gx = gridDim.x;
    const int nwg = gx * gridDim.y;
    const int orig = blockIdx.y * gx + blockIdx.x;
    const int q8 = nwg >> 3, r8 = nwg & 7;
    const int xcd = orig & 7, off8 = orig >> 3;
    const int wg = (xcd < r8 ? xcd * (q8 + 1) : r8 * (q8 + 1) + (xcd - r8) * q8) + off8;
    const int rowBase = (wg / gx) * TBM;
    const int colBase = (wg % gx) * BN;

    // shared pool: staging (As|Bs) during K-loop, C-tile in epilogue
    __shared__ __align__(16) __bf16 smem[ASZ + BSZ];
    auto As = (__bf16 (*)[TBM][KSTP])smem;
    auto Bs = (__bf16 (*)[BN][KSTP])(smem + ASZ);

    const int tid  = threadIdx.x;
    const int lane = tid & 63;
    const int w    = tid >> 6;
    const int fr   = lane & 15;
    const int fq   = lane >> 4;

    const int rowW = (TBM == 128) ? (w >> 1) * 64 : 0;
    const int colW = (TBM == 128) ? (w & 1) * 64  : w * 32;

    f32x4 acc[NI][NJ];
    const f32x4 zero = {0.f, 0.f, 0.f, 0.f};
    #pragma unroll
    for (int i = 0; i < NI; i++)
        #pragma unroll
        for (int j = 0; j < NJ; j++) acc[i][j] = zero;

    // prefetch registers (static-indexed only)
    bf16x8 pA[AE], pAl[AE], pB[BE], pBl[BE];
    float  pAf[AE * 8];

    auto issueAB = [&](int kt) {
        #pragma unroll
        for (int v = 0; v < AE; v++) {
            const int L = tid + v * 256;
            const long e = aOff + (long)(rowBase + (L >> 3)) * lda + kt + (L & 7) * 8;
            if constexpr (AMODE == 0) {
                pA[v] = *(const bf16x8*)(Ah + e);
                if (!f16m) pAl[v] = *(const bf16x8*)(Al + e);
            } else {
                load8(Araw, e, aDT, pAf + v * 8);
            }
        }
        #pragma unroll
        for (int v = 0; v < BE; v++) {
            const int L = tid + v * 256;
            const long e = bOff + (long)(colBase + (L >> 3)) * ldb + kt + (L & 7) * 8;
            pB[v] = *(const bf16x8*)(Bh + e);
            if (!f16m) pBl[v] = *(const bf16x8*)(Bl + e);
        }
    };
    // f16 mode: both A and B go into buffer `buf` (double-buffer).
    auto commit16 = [&](int buf) {
        #pragma unroll
        for (int v = 0; v < AE; v++) {
            const int L = tid + v * 256;
            if constexpr (AMODE == 0) {
                *(bf16x8*)&As[buf][L >> 3][(L & 7) * 8] = pA[v];
            } else {
                f16x8 h; pack8f16(pAf + v * 8, h);
                *(f16x8*)&As[buf][L >> 3][(L & 7) * 8] = h;
            }
        }
        #pragma unroll
        for (int v = 0; v < BE; v++) {
            const int L = tid + v * 256;
            *(bf16x8*)&Bs[buf][L >> 3][(L & 7) * 8] = pB[v];
        }
    };
    // f32 mode: slot 0 = hi plane, slot 1 = lo plane.
    auto commit32 = [&]() {
        #pragma unroll
        for (int v = 0; v < AE; v++) {
            const int L = tid + v * 256;
            if constexpr (AMODE == 0) {
                *(bf16x8*)&As[0][L >> 3][(L & 7) * 8] = pA[v];
                *(bf16x8*)&As[1][L >> 3][(L & 7) * 8] = pAl[v];
            } else {
                bf16x8 h, l; split8(pAf + v * 8, h, l);
                *(bf16x8*)&As[0][L >> 3][(L & 7) * 8] = h;
                *(bf16x8*)&As[1][L >> 3][(L & 7) * 8] = l;
            }
        }
        #pragma unroll
        for (int v = 0; v < BE; v++) {
            const int L = tid + v * 256;
            *(bf16x8*)&Bs[0][L >> 3][(L & 7) * 8] = pB[v];
            *(bf16x8*)&Bs[1][L >> 3][(L & 7) * 8] = pBl[v];
        }
    };

    if (f16m) {
        // ---- single-barrier double-buffered pipeline ----
        issueAB(0);
        commit16(0);
        __syncthreads();
        int cur = 0;
        for (int kt = 0; kt < K; kt += BK) {
            const bool haveNext = (kt + BK < K);
            if (haveNext) issueAB(kt + BK);
            __builtin_amdgcn_sched_barrier(0);

            f16x8 a16[NI][2], b16[NJ][2];
            #pragma unroll
            for (int c = 0; c < 2; c++) {
                #pragma unroll
                for (int i = 0; i < NI; i++)
                    a16[i][c] = *(const f16x8*)&As[cur][rowW + i * 16 + fr][c * 32 + fq * 8];
                #pragma unroll
                for (int j = 0; j < NJ; j++)
                    b16[j][c] = *(const f16x8*)&Bs[cur][colW + j * 16 + fr][c * 32 + fq * 8];
            }
            #pragma unroll
            for (int c = 0; c < 2; c++)
                #pragma unroll
                for (int i = 0; i < NI; i++)
                    #pragma unroll
                    for (int j = 0; j < NJ; j++)
                        acc[i][j] = mfma16h(a16[i][c], b16[j][c], acc[i][j]);

            if (haveNext) {
                commit16(cur ^ 1);
                __syncthreads();
                cur ^= 1;
            }
        }
    } else {
        // ---- legacy 2-barrier split-bf16 3-pass path ----
        issueAB(0);
        for (int kt = 0; kt < K; kt += BK) {
            commit32();
            __syncthreads();
            if (kt + BK < K) issueAB(kt + BK);
            __builtin_amdgcn_sched_barrier(0);

            #pragma unroll
            for (int c = 0; c < 2; c++) {
                bf16x8 ah[NI], al[NI], bh[NJ], bl[NJ];
                #pragma unroll
                for (int i = 0; i < NI; i++)
                    ah[i] = *(const bf16x8*)&As[0][rowW + i * 16 + fr][c * 32 + fq * 8];
                #pragma unroll
                for (int j = 0; j < NJ; j++)
                    bh[j] = *(const bf16x8*)&Bs[0][colW + j * 16 + fr][c * 32 + fq * 8];
                if (useALo)
                    #pragma unroll
                    for (int i = 0; i < NI; i++)
                        al[i] = *(const bf16x8*)&As[1][rowW + i * 16 + fr][c * 32 + fq * 8];
                if (useBLo)
                    #pragma unroll
                    for (int j = 0; j < NJ; j++)
                        bl[j] = *(const bf16x8*)&Bs[1][colW + j * 16 + fr][c * 32 + fq * 8];

                #pragma unroll
                for (int i = 0; i < NI; i++)
                    #pragma unroll
                    for (int j = 0; j < NJ; j++)
                        acc[i][j] = mfma16bf(ah[i], bh[j], acc[i][j]);
                if (useBLo)
                    #pragma unroll
                    for (int i = 0; i < NI; i++)
                        #pragma unroll
                        for (int j = 0; j < NJ; j++)
                            acc[i][j] = mfma16bf(ah[i], bl[j], acc[i][j]);
                if (useALo)
                    #pragma unroll
                    for (int i = 0; i < NI; i++)
                        #pragma unroll
                        for (int j = 0; j < NJ; j++)
                            acc[i][j] = mfma16bf(al[i], bh[j], acc[i][j]);
            }
            __syncthreads();
        }
    }
    __syncthreads();   // all frag reads done before epilogue reuses smem

    // ---- epilogue: LDS-staged, vector-flushed ------------------------------
    const int cDT = (EPI == 0) ? (f16m ? DT_F16 : DT_BF16) : resolveDT(cSel, mode);

    if (EPI == 1 && cDT == DT_F32) {
        float* ep = (float*)smem;
        #pragma unroll
        for (int half = 0; half < 2; half++) {
            if ((colW >> 6) == half) {
                #pragma unroll
                for (int i = 0; i < NI; i++)
                    #pragma unroll
                    for (int rr = 0; rr < 4; rr++) {
                        const int lrow = rowW + i * 16 + fq * 4 + rr;
                        #pragma unroll
                        for (int j = 0; j < NJ; j++) {
                            float v = acc[i][j][rr] * scale;
                            const int lcol = colW + j * 16 + fr;
                            if (CAUSAL) {
                                if (colBase + lcol > rowBase + lrow) v = maskval;
                            }
                            ep[lrow * EPAD4 + (lcol - half * 64)] = v;
                        }
                    }
            }
            __syncthreads();
            const int chunk = tid & 15, r0 = tid >> 4;
            for (int r = r0; r < TBM; r += 16) {
                float4 v = *(const float4*)&ep[(long)r * EPAD4 + chunk * 4];
                *(float4*)((float*)Craw + cOff + (long)(rowBase + r) * ldc
                           + colBase + half * 64 + chunk * 4) = v;
            }
            __syncthreads();
        }
    } else {
        const int planes = (EPI == 0 && !f16m) ? 2 : 1;
        for (int pl = 0; pl < planes; pl++) {
            #pragma unroll
            for (int i = 0; i < NI; i++)
                #pragma unroll
                for (int rr = 0; rr < 4; rr++) {
                    const int lrow = rowW + i * 16 + fq * 4 + rr;
                    #pragma unroll
                    for (int j = 0; j < NJ; j++) {
                        float v = acc[i][j][rr];
                        const int lcol = colW + j * 16 + fr;
                        if constexpr (EPI == 1) {
                            v *= scale;
                            if (CAUSAL) {
                                if (colBase + lcol > rowBase + lrow) v = maskval;
                            }
                        }
                        const long li = (long)lrow * EPAD + lcol;
                        if (cDT == DT_F16) {
                            ((_Float16*)smem)[li] = (_Float16)v;
                        } else {
                            __bf16 h = (__bf16)v;
                            ((__bf16*)smem)[li] = (pl == 0) ? h : (__bf16)(v - (float)h);
                        }
                    }
                }
            __syncthreads();
            __bf16* dst = (EPI == 1) ? (__bf16*)Craw : (pl == 0 ? Ch : Cl);
            const int chunk = tid & 15, r0 = tid >> 4;
            for (int r = r0; r < TBM; r += 16) {
                bf16x8 v = *(const bf16x8*)((const __bf16*)smem + (long)r * EPAD + chunk * 8);
                *(bf16x8*)(dst + cOff + (long)(rowBase + r) * ldc + colBase + chunk * 8) = v;
            }
            __syncthreads();
        }
    }
}

// ---------------------------------------------------------------------------
// In-place row softmax over attn region (reads SEL_SCORE, writes SEL_OUT)
__global__ __launch_bounds__(256)
void softmax_kernel(void* __restrict__ attn, long base, const int* __restrict__ flags)
{
    const int mode  = flags[0];
    const int rdDT  = resolveDT(SEL_SCORE, mode);
    const int wrDT  = resolveDT(SEL_OUT, mode);

    const int qrow = blockIdx.x;
    const int h    = blockIdx.y;
    const long row = base + ((long)h * S_ + qrow) * S_;
    const int tid  = threadIdx.x;
    const int wave = tid >> 6, lane = tid & 63;

    float vals[8];
    const bool v32 = (rdDT == DT_F32);
    const bool v16 = (rdDT == DT_F16);
    const long my8 = row + (long)tid * 8;
    if (v16) {
        f16x8 v = *(const f16x8*)((const _Float16*)attn + my8);
        #pragma unroll
        for (int j = 0; j < 8; j++) vals[j] = (float)v[j];
    } else if (v32) {
        const float4* rp = (const float4*)((const float*)attn + row);
        float4 a = rp[tid], b = rp[tid + 256];
        vals[0]=a.x; vals[1]=a.y; vals[2]=a.z; vals[3]=a.w;
        vals[4]=b.x; vals[5]=b.y; vals[6]=b.z; vals[7]=b.w;
    } else {
        #pragma unroll
        for (int i = 0; i < 8; i++)
            vals[i] = loadF(attn, row + tid + i * 256, rdDT);
    }

    float m = -3.4e38f;
    #pragma unroll
    for (int i = 0; i < 8; i++) m = fmaxf(m, vals[i]);
    #pragma unroll
    for (int off = 32; off > 0; off >>= 1)
        m = fmaxf(m, __shfl_down(m, off, 64));
    __shared__ float redm[4];
    if (lane == 0) redm[wave] = m;
    __syncthreads();
    if (tid == 0) redm[0] = fmaxf(fmaxf(redm[0], redm[1]), fmaxf(redm[2], redm[3]));
    __syncthreads();
    m = redm[0];

    float s = 0.f;
    #pragma unroll
    for (int i = 0; i < 8; i++) {
        vals[i] = __expf(vals[i] - m);
        s += vals[i];
    }
    #pragma unroll
    for (int off = 32; off > 0; off >>= 1)
        s += __shfl_down(s, off, 64);
    __shared__ float reds[4];
    if (lane == 0) reds[wave] = s;
    __syncthreads();
    if (tid == 0) reds[0] = reds[0] + reds[1] + reds[2] + reds[3];
    __syncthreads();
    const float inv = 1.f / reds[0];

    if (v16 && wrDT == DT_BF16) {
        bf16x8 o;
        #pragma unroll
        for (int j = 0; j < 8; j++) o[j] = (__bf16)(vals[j] * inv);
        *(bf16x8*)((__bf16*)attn + my8) = o;
    } else if (v32 && wrDT == DT_F32) {
        float4* wp = (float4*)((float*)attn + row);
        float4 a, b;
        a.x=vals[0]*inv; a.y=vals[1]*inv; a.z=vals[2]*inv; a.w=vals[3]*inv;
        b.x=vals[4]*inv; b.y=vals[5]*inv; b.z=vals[6]*inv; b.w=vals[7]*inv;
        wp[tid] = a; wp[tid + 256] = b;
    } else {
        #pragma unroll
        for (int i = 0; i < 8; i++)
            storeF(attn, row + tid + i * 256, wrDT, vals[i] * inv);
    }
}

// ---------------------------------------------------------------------------
extern "C" void kernel_launch(void* const* d_in, const int* in_sizes, int n_in,
                              void* d_out, int out_size, void* d_ws, size_t ws_size,
                              hipStream_t stream)
{
    (void)in_sizes; (void)n_in; (void)out_size; (void)ws_size;

    const void* hidden = d_in[0];
    const void* qb     = d_in[1];
    const void* kb     = d_in[2];
    const void* vb     = d_in[3];
    const void* ob     = d_in[4];
    const void* act    = d_in[5];

    const long ATTN_BASE = (long)S_ * TD;

    // Workspace: operand planes (~59 MB), with buffer reuse across phases
    const long PLANE = (long)S_ * H_;        // 4M elems
    const long SMALL = (long)ROOM * H_;      // 0.5M elems
    __bf16* p = (__bf16*)d_ws;
    __bf16* hidH = p;               __bf16* hidL = hidH + PLANE;  // hidden planes
    __bf16* aoH  = hidH;            __bf16* aoL  = hidL;          // reuse: attn_out planes
    __bf16* qbH  = p + 2 * PLANE;   __bf16* qbL  = qbH + PLANE;   // gathered q_block planes
    __bf16* otH  = qbH;             __bf16* otL  = qbL;           // reuse: o_block^T planes
    __bf16* qfH  = p + 4 * PLANE;   __bf16* qfL  = qfH + PLANE;   // qf planes [S][TD]
    __bf16* kbH  = p + 6 * PLANE;   __bf16* kbL  = kbH + SMALL;   // k_block planes
    __bf16* vbH  = kbL + SMALL;     __bf16* vbL  = vbH + SMALL;   // v_block planes
    __bf16* k1H  = vbL + SMALL;     __bf16* k1L  = k1H + SMALL;   // k_one planes [S][ROOM]
    __bf16* vtH  = k1L + SMALL;     __bf16* vtL  = vtH + SMALL;   // v_one^T planes [ROOM][S]
    int* map   = (int*)(vtL + SMALL);
    int* flags = map + TD;

    const float inv_sqrt_hd = 0.08838834764831845f;

    setup_kernel<<<1, 256, 0, stream>>>(hidden, act, map, flags);

    // input -> plane conversions
    conv_plain<<<dim3((unsigned)(PLANE / 2048)), 256, 0, stream>>>(hidden, hidH, hidL, flags);
    conv_gather<<<dim3(TD), 256, 0, stream>>>(qb, qbH, qbL, map, flags);
    conv_plain<<<dim3((unsigned)(SMALL / 2048)), 256, 0, stream>>>(kb, kbH, kbL, flags);
    conv_plain<<<dim3((unsigned)(SMALL / 2048)), 256, 0, stream>>>(vb, vbH, vbL, flags);

    // G1: qf = hidden x qB^T          M=S, N=TD, K=H      (512 blocks, 2/CU)
    mgemm<64, 0, 0, false><<<dim3(TD / BN, S_ / 64, 1), 256, 0, stream>>>(
        hidH, hidL, nullptr, 0, qbH, qbL, qfH, qfL, nullptr, 0,
        H_, H_, H_, TD, 0, 0, 0, 0, 0, 0, 0, flags, 1, 1, 1.f, 0.f);

    // G2: k_one = hidden x kB^T       M=S, N=ROOM, K=H
    mgemm<64, 0, 0, false><<<dim3(ROOM / BN, S_ / 64, 1), 256, 0, stream>>>(
        hidH, hidL, nullptr, 0, kbH, kbL, k1H, k1L, nullptr, 0,
        H_, H_, H_, ROOM, 0, 0, 0, 0, 0, 0, 0, flags, 1, 1, 1.f, 0.f);

    // G3: v_one^T = v_block x hidden^T   M=ROOM, N=S, K=H  (transposed for free)
    mgemm<64, 0, 0, false><<<dim3(S_ / BN, ROOM / 64, 1), 256, 0, stream>>>(
        vbH, vbL, nullptr, 0, hidH, hidL, vtH, vtL, nullptr, 0,
        H_, H_, H_, S_, 0, 0, 0, 0, 0, 0, 0, flags, 1, 1, 1.f, 0.f);

    // G4: raw causal scores per head -> d_out attn region   K=HD (2 K-steps)
    mgemm<128, 0, 1, true><<<dim3(S_ / BN, S_ / 128, NH), 256, 0, stream>>>(
        qfH, qfL, nullptr, 0, k1H, k1L, nullptr, nullptr, d_out, SEL_SCORE,
        HD, TD, ROOM, S_, 0, 0, ATTN_BASE,
        (long)HD, (long)HD, 1, (long)S_ * S_, flags, 0, 0, inv_sqrt_hd, -1e4f);

    // G5: softmax in-place (graded attention weights)
    softmax_kernel<<<dim3(S_, NH), 256, 0, stream>>>(d_out, ATTN_BASE, flags);

    // o_block gather+transpose planes (qB buffer is dead now)
    conv_gatherT<<<dim3(TD / 64, H_ / 64), 256, 0, stream>>>(ob, otH, otL, map, flags);

    // G6: attn_out = P x v_one^T^T    per head: M=S, N=HD, K=S  (512 blocks)
    mgemm<64, 1, 0, false><<<dim3(HD / BN, S_ / 64, NH), 256, 0, stream>>>(
        nullptr, nullptr, d_out, SEL_OUT, vtH, vtL, aoH, aoL, nullptr, 0,
        S_, S_, S_, TD, ATTN_BASE, 0, 0,
        (long)S_ * S_, (long)HD * S_, 1, (long)HD, flags, 1, 0, 1.f, 0.f);

    // G7: o_out = attn_out x oT^T     M=S, N=H, K=TD      (512 blocks, 2/CU)
    mgemm<64, 0, 1, false><<<dim3(H_ / BN, S_ / 64, 1), 256, 0, stream>>>(
        aoH, aoL, nullptr, 0, otH, otL, nullptr, nullptr, d_out, SEL_OUT,
        TD, TD, TD, H_, 0, 0, 0, 0, 0, 0, 0, flags, 0, 1, 1.f, 0.f);
}